// Round 1
// baseline (995.018 us; speedup 1.0000x reference)
//
#include <hip/hip_runtime.h>

typedef __attribute__((ext_vector_type(8))) __bf16 bf16x8;
typedef __attribute__((ext_vector_type(4))) float f32x4;

constexpr int BATCH = 16384;
constexpr int DIN   = 1024;
constexpr int DHID  = 1000;
constexpr int DHIDP = 1024;   // padded hidden (cols 1000..1023 zero)
constexpr int MAXA  = 3129;

// ws layout
constexpr size_t WS_H   = 0;                        // bf16 H [16384][1024] = 33,554,432 B
constexpr size_t WS_CNT = 33554432;                 // 3 ints (64B slot)
constexpr size_t WS_IDX = WS_CNT + 64;              // int idx [3][16384]

__device__ __forceinline__ ushort f2bf(float f) {
    unsigned u = __builtin_bit_cast(unsigned, f);
    u += 0x7fffu + ((u >> 16) & 1u);
    return (ushort)(u >> 16);
}

__global__ void route_k(const float* __restrict__ qt, int* __restrict__ counts,
                        int* __restrict__ idx) {
    int i = blockIdx.x * 256 + threadIdx.x;
    if (i >= BATCH) return;
    float a = qt[3 * i], b = qt[3 * i + 1], c = qt[3 * i + 2];
    int p = 0; float m = a;
    if (b > m) { m = b; p = 1; }
    if (c > m) { m = c; p = 2; }
    int pos = atomicAdd(&counts[p], 1);
    idx[p * BATCH + pos] = i;
}

// ---------------- GEMM1: H[rows] = tanh(hs[rows] @ W1 + b1), bf16 out ----------------
// grid (8 Nblk, 128 Mblk), block 256 (4 waves, 2x2 wave grid, 64x64/wave)
__global__ __launch_bounds__(256)
void gemm1_k(const float* __restrict__ A, const float* __restrict__ W,
             const float* __restrict__ bias, const int* __restrict__ cntp,
             const int* __restrict__ idx, ushort* __restrict__ H) {
    const int cnt = *cntp;
    const int m0 = blockIdx.y * 128;
    if (m0 >= cnt) return;
    const int n0 = blockIdx.x * 128;
    const int tid = threadIdx.x;
    const int lane = tid & 63;
    const int wid = tid >> 6, wm = wid >> 1, wn = wid & 1;

    __shared__ ushort Asm[128][40];     // row-major, pad 32->40 (2-way max aliasing)
    __shared__ ushort Bsm[4][128][8];   // k-packed-8: [kc][n][e]
    __shared__ int rows[128];

    if (tid < 128) { int rr = m0 + tid; if (rr >= cnt) rr = cnt - 1; rows[tid] = idx[rr]; }
    __syncthreads();

    f32x4 acc[4][4];
    const f32x4 z = {0.f, 0.f, 0.f, 0.f};
#pragma unroll
    for (int mi = 0; mi < 4; mi++)
#pragma unroll
        for (int ni = 0; ni < 4; ni++) acc[mi][ni] = z;

    for (int kt = 0; kt < DIN / 32; ++kt) {
        const int k0 = kt * 32;
        // stage A: [128 rows][32 k] f32 -> bf16
#pragma unroll
        for (int i = 0; i < 4; ++i) {
            int lin = tid + 256 * i;
            int r = lin >> 3, c4 = (lin & 7) * 4;
            const float4 v = *reinterpret_cast<const float4*>(A + (size_t)rows[r] * DIN + k0 + c4);
            ushort4 b4; b4.x = f2bf(v.x); b4.y = f2bf(v.y); b4.z = f2bf(v.z); b4.w = f2bf(v.w);
            *reinterpret_cast<ushort4*>(&Asm[r][c4]) = b4;
        }
        // stage B: [32 k][128 n] from W (stride DHID), n>=DHID -> 0
#pragma unroll
        for (int i = 0; i < 4; ++i) {
            int lin = tid + 256 * i;
            int k = lin >> 5, n4 = (lin & 31) * 4;
            int n = n0 + n4;
            float vv[4];
            if (n + 3 < DHID) {
                const float4 v = *reinterpret_cast<const float4*>(W + (size_t)(k0 + k) * DHID + n);
                vv[0] = v.x; vv[1] = v.y; vv[2] = v.z; vv[3] = v.w;
            } else {
#pragma unroll
                for (int j = 0; j < 4; j++) vv[j] = (n + j < DHID) ? W[(size_t)(k0 + k) * DHID + n + j] : 0.f;
            }
            int kc = k >> 3, e = k & 7;
#pragma unroll
            for (int j = 0; j < 4; j++) Bsm[kc][n4 + j][e] = f2bf(vv[j]);
        }
        __syncthreads();

        bf16x8 af[4], bfr[4];
        const int arow = lane & 15, akb = (lane >> 4) * 8;
#pragma unroll
        for (int mi = 0; mi < 4; mi++)
            af[mi] = *reinterpret_cast<const bf16x8*>(&Asm[wm * 64 + mi * 16 + arow][akb]);
#pragma unroll
        for (int ni = 0; ni < 4; ni++)
            bfr[ni] = *reinterpret_cast<const bf16x8*>(&Bsm[lane >> 4][wn * 64 + ni * 16 + (lane & 15)][0]);
#pragma unroll
        for (int mi = 0; mi < 4; mi++)
#pragma unroll
            for (int ni = 0; ni < 4; ni++)
                acc[mi][ni] = __builtin_amdgcn_mfma_f32_16x16x32_bf16(af[mi], bfr[ni], acc[mi][ni], 0, 0, 0);
        __syncthreads();
    }

#pragma unroll
    for (int mi = 0; mi < 4; mi++) {
        const int mbase = wm * 64 + mi * 16 + ((lane >> 4) << 2);
#pragma unroll
        for (int ni = 0; ni < 4; ni++) {
            const int ncol = n0 + wn * 64 + ni * 16 + (lane & 15);
#pragma unroll
            for (int r = 0; r < 4; r++) {
                const int ml = mbase + r;
                if (m0 + ml < cnt) {
                    float v = 0.f;
                    if (ncol < DHID) v = tanhf(acc[mi][ni][r] + bias[ncol]);
                    H[(size_t)rows[ml] * DHIDP + ncol] = f2bf(v);
                }
            }
        }
    }
}

// ---------------- GEMM2: out[rows, :ne] = H[rows] @ W2 + b2 ; rest of row = 0 --------
// grid (25 Nblk, 128 Mblk), block 256
__global__ __launch_bounds__(256)
void gemm2_k(const ushort* __restrict__ H, const float* __restrict__ W,
             const float* __restrict__ bias, const int* __restrict__ cntp,
             const int* __restrict__ idx, int ne, float* __restrict__ Out) {
    const int cnt = *cntp;
    const int m0 = blockIdx.y * 128;
    if (m0 >= cnt) return;
    const int n0 = blockIdx.x * 128;
    const int tid = threadIdx.x;

    __shared__ ushort Asm[128][40];
    __shared__ ushort Bsm[4][128][8];
    __shared__ int rows[128];

    if (tid < 128) { int rr = m0 + tid; if (rr >= cnt) rr = cnt - 1; rows[tid] = idx[rr]; }
    __syncthreads();

    if (n0 >= ne) {  // pure zero-fill block
        const int nend = (n0 + 128 < MAXA) ? n0 + 128 : MAXA;
        const int width = nend - n0;
        const int nrow = (cnt - m0 < 128) ? cnt - m0 : 128;
        if (width == 128) {
            for (int t = tid; t < (nrow << 7); t += 256) {
                int r = t >> 7, n = t & 127;
                Out[(size_t)rows[r] * MAXA + n0 + n] = 0.f;
            }
        } else {
            const int tot = nrow * width;
            for (int t = tid; t < tot; t += 256) {
                int r = t / width, n = t - r * width;
                Out[(size_t)rows[r] * MAXA + n0 + n] = 0.f;
            }
        }
        return;
    }

    const int lane = tid & 63;
    const int wid = tid >> 6, wm = wid >> 1, wn = wid & 1;

    f32x4 acc[4][4];
    const f32x4 z = {0.f, 0.f, 0.f, 0.f};
#pragma unroll
    for (int mi = 0; mi < 4; mi++)
#pragma unroll
        for (int ni = 0; ni < 4; ni++) acc[mi][ni] = z;

    for (int kt = 0; kt < DHIDP / 32; ++kt) {
        const int k0 = kt * 32;
        // stage A from H (already bf16, cols>=1000 are zero)
#pragma unroll
        for (int i = 0; i < 2; ++i) {
            int lin = tid + 256 * i;
            int r = lin >> 2, c = (lin & 3) * 8;
            const int4 v = *reinterpret_cast<const int4*>(H + (size_t)rows[r] * DHIDP + k0 + c);
            *reinterpret_cast<int4*>(&Asm[r][c]) = v;
        }
        // stage B: W2 [1000][ne], stride ne (odd) -> scalar loads, guards k<1000, n<ne
#pragma unroll
        for (int i = 0; i < 4; ++i) {
            int lin = tid + 256 * i;
            int k = lin >> 5, n4 = (lin & 31) * 4;
            const int kk = k0 + k;
            const int kc = k >> 3, e = k & 7;
#pragma unroll
            for (int j = 0; j < 4; j++) {
                const int nn = n0 + n4 + j;
                float v = (kk < DHID && nn < ne) ? W[(size_t)kk * ne + nn] : 0.f;
                Bsm[kc][n4 + j][e] = f2bf(v);
            }
        }
        __syncthreads();

        bf16x8 af[4], bfr[4];
        const int arow = lane & 15, akb = (lane >> 4) * 8;
#pragma unroll
        for (int mi = 0; mi < 4; mi++)
            af[mi] = *reinterpret_cast<const bf16x8*>(&Asm[wm * 64 + mi * 16 + arow][akb]);
#pragma unroll
        for (int ni = 0; ni < 4; ni++)
            bfr[ni] = *reinterpret_cast<const bf16x8*>(&Bsm[lane >> 4][wn * 64 + ni * 16 + (lane & 15)][0]);
#pragma unroll
        for (int mi = 0; mi < 4; mi++)
#pragma unroll
            for (int ni = 0; ni < 4; ni++)
                acc[mi][ni] = __builtin_amdgcn_mfma_f32_16x16x32_bf16(af[mi], bfr[ni], acc[mi][ni], 0, 0, 0);
        __syncthreads();
    }

#pragma unroll
    for (int mi = 0; mi < 4; mi++) {
        const int mbase = wm * 64 + mi * 16 + ((lane >> 4) << 2);
#pragma unroll
        for (int ni = 0; ni < 4; ni++) {
            const int ncol = n0 + wn * 64 + ni * 16 + (lane & 15);
            if (ncol >= MAXA) continue;
            const bool live = ncol < ne;
            const float bv = live ? bias[ncol] : 0.f;
#pragma unroll
            for (int r = 0; r < 4; r++) {
                const int ml = mbase + r;
                if (m0 + ml < cnt) {
                    float v = live ? (acc[mi][ni][r] + bv) : 0.f;
                    Out[(size_t)rows[ml] * MAXA + ncol] = v;
                }
            }
        }
    }
}

extern "C" void kernel_launch(void* const* d_in, const int* in_sizes, int n_in,
                              void* d_out, int out_size, void* d_ws, size_t ws_size,
                              hipStream_t stream) {
    const float* hs = (const float*)d_in[0];
    const float* qt = (const float*)d_in[1];
    const float* w1[3] = {(const float*)d_in[2], (const float*)d_in[6], (const float*)d_in[10]};
    const float* b1[3] = {(const float*)d_in[3], (const float*)d_in[7], (const float*)d_in[11]};
    const float* w2[3] = {(const float*)d_in[4], (const float*)d_in[8], (const float*)d_in[12]};
    const float* b2[3] = {(const float*)d_in[5], (const float*)d_in[9], (const float*)d_in[13]};
    const int ne[3] = {2, 482, 3129};

    char* ws = (char*)d_ws;
    ushort* H = (ushort*)(ws + WS_H);
    int* counts = (int*)(ws + WS_CNT);
    int* idx = (int*)(ws + WS_IDX);
    float* Out = (float*)d_out;

    hipMemsetAsync(counts, 0, 3 * sizeof(int), stream);
    route_k<<<(BATCH + 255) / 256, 256, 0, stream>>>(qt, counts, idx);
    for (int e = 0; e < 3; e++)
        gemm1_k<<<dim3(8, 128), 256, 0, stream>>>(hs, w1[e], b1[e], counts + e, idx + e * BATCH, H);
    for (int e = 0; e < 3; e++)
        gemm2_k<<<dim3(25, 128), 256, 0, stream>>>(H, w2[e], b2[e], counts + e, idx + e * BATCH, ne[e], Out);
}

// Round 2
// 403.859 us; speedup vs baseline: 2.4638x; 2.4638x over previous
//
#include <hip/hip_runtime.h>

typedef __attribute__((ext_vector_type(8))) __bf16 bf16x8;
typedef __attribute__((ext_vector_type(4))) float f32x4;

constexpr int BATCH = 16384;
constexpr int DIN   = 1024;
constexpr int DHID  = 1000;
constexpr int MAXA  = 3129;

// packed tile: [kt][kc(4)][rc(128)][e8(8)] bf16, 8KB per (tile,kt)
// ws layout (bytes)
constexpr size_t WS_HP  = 0;                         // Hp: 130 blk x 32 kt x 8KB = 34,078,720
constexpr size_t WS_W1P = 34078720;                  // W1p: 3 e x 8 nb x 32 kt x 8KB = 6,291,456
constexpr size_t WS_W2P = 40370176;                  // W2p: 30 nb-tiles x 32 kt x 8KB = 7,864,320
constexpr size_t WS_CNT = 48234496;                  // 3 ints (64B)
constexpr size_t WS_IDX = 48234560;                  // int[3][16384]

__device__ __forceinline__ ushort f2bf(float f) {
    return __builtin_bit_cast(ushort, (__bf16)f);
}

__device__ __forceinline__ void gload16(const void* g, void* l) {
    __builtin_amdgcn_global_load_lds((const __attribute__((address_space(1))) void*)g,
                                     (__attribute__((address_space(3))) void*)l, 16, 0, 0);
}

__global__ void route_k(const float* __restrict__ qt, int* __restrict__ counts,
                        int* __restrict__ idx) {
    int i = blockIdx.x * 256 + threadIdx.x;
    if (i >= BATCH) return;
    float a = qt[3 * i], b = qt[3 * i + 1], c = qt[3 * i + 2];
    int p = 0; float m = a;
    if (b > m) { m = b; p = 1; }
    if (c > m) { m = c; p = 2; }
    int pos = atomicAdd(&counts[p], 1);
    idx[p * BATCH + pos] = i;
}

// pack W1 (f32 [1024][1000], k-major) -> W1p[e][nb(8)][kt(32)][kc][n128][e8] bf16
__global__ void pack_w1_k(const float* __restrict__ w1_0, const float* __restrict__ w1_1,
                          const float* __restrict__ w1_2, ushort* __restrict__ W1p) {
    int g = blockIdx.x * 256 + threadIdx.x;         // [e][nb][kt][kc][n]
    int n = g & 127, kc = (g >> 7) & 3, kt = (g >> 9) & 31, nb = (g >> 14) & 7, e = g >> 17;
    const float* W = e == 0 ? w1_0 : e == 1 ? w1_1 : w1_2;
    int nn = nb * 128 + n;
    union { ushort u[8]; int4 v; } p;
#pragma unroll
    for (int j = 0; j < 8; j++) {
        int k = kt * 32 + kc * 8 + j;
        float f = (nn < DHID) ? W[(size_t)k * DHID + nn] : 0.f;
        p.u[j] = f2bf(f);
    }
    size_t off = ((size_t)((e * 8 + nb) * 32 + kt)) * 4096 + (kc * 128 + n) * 8;  // ushort units
    *reinterpret_cast<int4*>(W1p + off) = p.v;
}

// pack W2 (f32 [1000][ne]) -> W2p[t(30)][kt(32)][kc][n128][e8]; t->(e,nb): e0:t0, e1:t1-4, e2:t5-29
__global__ void pack_w2_k(const float* __restrict__ w2_0, const float* __restrict__ w2_1,
                          const float* __restrict__ w2_2, ushort* __restrict__ W2p) {
    int g = blockIdx.x * 256 + threadIdx.x;         // [t][kt][kc][n]
    int n = g & 127, kc = (g >> 7) & 3, kt = (g >> 9) & 31, t = g >> 14;
    int e = (t < 1) ? 0 : (t < 5) ? 1 : 2;
    int nb = t - (e == 0 ? 0 : e == 1 ? 1 : 5);
    int ne = e == 0 ? 2 : e == 1 ? 482 : MAXA;
    const float* W = e == 0 ? w2_0 : e == 1 ? w2_1 : w2_2;
    int nn = nb * 128 + n;
    union { ushort u[8]; int4 v; } p;
#pragma unroll
    for (int j = 0; j < 8; j++) {
        int k = kt * 32 + kc * 8 + j;
        float f = (k < DHID && nn < ne) ? W[(size_t)k * ne + nn] : 0.f;
        p.u[j] = f2bf(f);
    }
    size_t off = ((size_t)(t * 32 + kt)) * 4096 + (kc * 128 + n) * 8;
    *reinterpret_cast<int4*>(W2p + off) = p.v;
}

// ---------------- GEMM1: Hp[pos-block] = tanh(hs[rows] @ W1 + b1), packed bf16 out ----
__global__ __launch_bounds__(256)
void gemm1_k(const float* __restrict__ hs, const ushort* __restrict__ W1p,
             const float* __restrict__ b1_0, const float* __restrict__ b1_1,
             const float* __restrict__ b1_2,
             const int* __restrict__ counts, const int* __restrict__ idx,
             ushort* __restrict__ Hp) {
    const int c0 = counts[0], c1 = counts[1], c2 = counts[2];
    const int nb0 = (c0 + 127) >> 7, nb1 = (c1 + 127) >> 7, nb2 = (c2 + 127) >> 7;
    const int by = blockIdx.y;
    int e, lm, cnt;
    if (by < nb0) { e = 0; lm = by; cnt = c0; }
    else if (by < nb0 + nb1) { e = 1; lm = by - nb0; cnt = c1; }
    else if (by < nb0 + nb1 + nb2) { e = 2; lm = by - nb0 - nb1; cnt = c2; }
    else return;
    const float* bias = e == 0 ? b1_0 : e == 1 ? b1_1 : b1_2;
    const int nb = blockIdx.x;
    const int tid = threadIdx.x;
    const int lane = tid & 63, w = tid >> 6;
    const int wm = w >> 1, wn = w & 1;

    __shared__ ushort Ab[2][4][128][8];
    __shared__ ushort Bb[2][4][128][8];
    __shared__ int rows[128];
    if (tid < 128) { int rr = lm * 128 + tid; if (rr >= cnt) rr = cnt - 1; rows[tid] = idx[e * BATCH + rr]; }
    __syncthreads();

    const int m_t = tid & 127, half = tid >> 7;
    const float* Arow = hs + (size_t)rows[m_t] * DIN;
    const ushort* Btile = W1p + (size_t)((e * 8 + nb) * 32) * 4096;

    f32x4 acc[4][4] = {};

    auto stage = [&](int b, int kt) {
        const float* ap = Arow + kt * 32 + half * 16;
#pragma unroll
        for (int i = 0; i < 2; ++i) {
            const int kc = half * 2 + i;
            float4 f0 = *reinterpret_cast<const float4*>(ap + i * 8);
            float4 f1 = *reinterpret_cast<const float4*>(ap + i * 8 + 4);
            union { ushort u[8]; int4 v; } p;
            p.u[0] = f2bf(f0.x); p.u[1] = f2bf(f0.y); p.u[2] = f2bf(f0.z); p.u[3] = f2bf(f0.w);
            p.u[4] = f2bf(f1.x); p.u[5] = f2bf(f1.y); p.u[6] = f2bf(f1.z); p.u[7] = f2bf(f1.w);
            *reinterpret_cast<int4*>(&Ab[b][kc][m_t][0]) = p.v;
        }
        const char* bs = (const char*)(Btile + (size_t)kt * 4096) + w * 2048 + lane * 16;
        char* bd = (char*)&Bb[b][0][0][0] + w * 2048;
        gload16(bs, bd);
        gload16(bs + 1024, bd + 1024);
    };
    auto compute = [&](int b) {
        bf16x8 af[4], bfr[4];
        const int kq = lane >> 4, l15 = lane & 15;
#pragma unroll
        for (int mi = 0; mi < 4; mi++) af[mi] = *reinterpret_cast<const bf16x8*>(&Ab[b][kq][wm * 64 + mi * 16 + l15][0]);
#pragma unroll
        for (int ni = 0; ni < 4; ni++) bfr[ni] = *reinterpret_cast<const bf16x8*>(&Bb[b][kq][wn * 64 + ni * 16 + l15][0]);
#pragma unroll
        for (int mi = 0; mi < 4; mi++)
#pragma unroll
            for (int ni = 0; ni < 4; ni++)
                acc[mi][ni] = __builtin_amdgcn_mfma_f32_16x16x32_bf16(af[mi], bfr[ni], acc[mi][ni], 0, 0, 0);
    };

    stage(0, 0);
    __syncthreads();
    for (int kt = 0; kt < 32; ++kt) {
        const int cb = kt & 1;
        if (kt + 1 < 32) stage(cb ^ 1, kt + 1);
        compute(cb);
        __syncthreads();
    }

    ushort* Hblk = Hp + (size_t)by * (32 * 4096);
#pragma unroll
    for (int mi = 0; mi < 4; mi++) {
        const int mb = wm * 64 + mi * 16 + ((lane >> 4) << 2);
#pragma unroll
        for (int ni = 0; ni < 4; ni++) {
            const int nl = wn * 64 + ni * 16 + (lane & 15);
            const int n = nb * 128 + nl;
            const bool live = n < DHID;
            const float bv = live ? bias[n] : 0.f;
#pragma unroll
            for (int r = 0; r < 4; r++) {
                const int m = mb + r;
                float v = live ? tanhf(acc[mi][ni][r] + bv) : 0.f;
                Hblk[(size_t)(n >> 5) * 4096 + (((n >> 3) & 3) * 128 + m) * 8 + (n & 7)] = f2bf(v);
            }
        }
    }
}

// ---------------- GEMM2: Out[rows, :ne] = Hp @ W2 + b2 (dead cols pre-zeroed) --------
__global__ __launch_bounds__(256)
void gemm2_k(const ushort* __restrict__ Hp, const ushort* __restrict__ W2p,
             const float* __restrict__ b2_0, const float* __restrict__ b2_1,
             const float* __restrict__ b2_2,
             const int* __restrict__ counts, const int* __restrict__ idx,
             float* __restrict__ Out) {
    const int c0 = counts[0], c1 = counts[1], c2 = counts[2];
    const int nb0 = (c0 + 127) >> 7, nb1 = (c1 + 127) >> 7, nb2 = (c2 + 127) >> 7;
    const int by = blockIdx.y;
    int e, lm, cnt;
    if (by < nb0) { e = 0; lm = by; cnt = c0; }
    else if (by < nb0 + nb1) { e = 1; lm = by - nb0; cnt = c1; }
    else if (by < nb0 + nb1 + nb2) { e = 2; lm = by - nb0 - nb1; cnt = c2; }
    else return;
    const int nbn = e == 0 ? 1 : e == 1 ? 4 : 25;
    const int nb = blockIdx.x;
    if (nb >= nbn) return;
    const int toff = e == 0 ? 0 : e == 1 ? 1 : 5;
    const int ne = e == 0 ? 2 : e == 1 ? 482 : MAXA;
    const float* bias = e == 0 ? b2_0 : e == 1 ? b2_1 : b2_2;
    const int tid = threadIdx.x;
    const int lane = tid & 63, w = tid >> 6;
    const int wm = w >> 1, wn = w & 1;

    __shared__ ushort Ab[2][4][128][8];
    __shared__ ushort Bb[2][4][128][8];
    __shared__ int rows[128];
    if (tid < 128) { int rr = lm * 128 + tid; if (rr >= cnt) rr = cnt - 1; rows[tid] = idx[e * BATCH + rr]; }

    const ushort* Atile = Hp + (size_t)by * (32 * 4096);
    const ushort* Btile = W2p + (size_t)((toff + nb) * 32) * 4096;

    f32x4 acc[4][4] = {};

    auto stage = [&](int b, int kt) {
        const char* as = (const char*)(Atile + (size_t)kt * 4096) + w * 2048 + lane * 16;
        char* ad = (char*)&Ab[b][0][0][0] + w * 2048;
        gload16(as, ad);
        gload16(as + 1024, ad + 1024);
        const char* bs = (const char*)(Btile + (size_t)kt * 4096) + w * 2048 + lane * 16;
        char* bd = (char*)&Bb[b][0][0][0] + w * 2048;
        gload16(bs, bd);
        gload16(bs + 1024, bd + 1024);
    };
    auto compute = [&](int b) {
        bf16x8 af[4], bfr[4];
        const int kq = lane >> 4, l15 = lane & 15;
#pragma unroll
        for (int mi = 0; mi < 4; mi++) af[mi] = *reinterpret_cast<const bf16x8*>(&Ab[b][kq][wm * 64 + mi * 16 + l15][0]);
#pragma unroll
        for (int ni = 0; ni < 4; ni++) bfr[ni] = *reinterpret_cast<const bf16x8*>(&Bb[b][kq][wn * 64 + ni * 16 + l15][0]);
#pragma unroll
        for (int mi = 0; mi < 4; mi++)
#pragma unroll
            for (int ni = 0; ni < 4; ni++)
                acc[mi][ni] = __builtin_amdgcn_mfma_f32_16x16x32_bf16(af[mi], bfr[ni], acc[mi][ni], 0, 0, 0);
    };

    stage(0, 0);
    __syncthreads();
    for (int kt = 0; kt < 32; ++kt) {
        const int cb = kt & 1;
        if (kt + 1 < 32) stage(cb ^ 1, kt + 1);
        compute(cb);
        __syncthreads();
    }

    const int m0 = lm * 128;
#pragma unroll
    for (int mi = 0; mi < 4; mi++) {
        const int mb = wm * 64 + mi * 16 + ((lane >> 4) << 2);
#pragma unroll
        for (int ni = 0; ni < 4; ni++) {
            const int ncol = nb * 128 + wn * 64 + ni * 16 + (lane & 15);
            if (ncol >= ne) continue;
            const float bv = bias[ncol];
#pragma unroll
            for (int r = 0; r < 4; r++) {
                const int ml = mb + r;
                if (m0 + ml < cnt) Out[(size_t)rows[ml] * MAXA + ncol] = acc[mi][ni][r] + bv;
            }
        }
    }
}

extern "C" void kernel_launch(void* const* d_in, const int* in_sizes, int n_in,
                              void* d_out, int out_size, void* d_ws, size_t ws_size,
                              hipStream_t stream) {
    const float* hs = (const float*)d_in[0];
    const float* qt = (const float*)d_in[1];
    const float* w1_0 = (const float*)d_in[2],  *b1_0 = (const float*)d_in[3];
    const float* w2_0 = (const float*)d_in[4],  *b2_0 = (const float*)d_in[5];
    const float* w1_1 = (const float*)d_in[6],  *b1_1 = (const float*)d_in[7];
    const float* w2_1 = (const float*)d_in[8],  *b2_1 = (const float*)d_in[9];
    const float* w1_2 = (const float*)d_in[10], *b1_2 = (const float*)d_in[11];
    const float* w2_2 = (const float*)d_in[12], *b2_2 = (const float*)d_in[13];

    char* ws = (char*)d_ws;
    ushort* Hp  = (ushort*)(ws + WS_HP);
    ushort* W1p = (ushort*)(ws + WS_W1P);
    ushort* W2p = (ushort*)(ws + WS_W2P);
    int* counts = (int*)(ws + WS_CNT);
    int* idx    = (int*)(ws + WS_IDX);
    float* Out  = (float*)d_out;

    hipMemsetAsync(counts, 0, 64, stream);
    route_k<<<64, 256, 0, stream>>>(qt, counts, idx);
    pack_w1_k<<<1536, 256, 0, stream>>>(w1_0, w1_1, w1_2, W1p);
    pack_w2_k<<<1920, 256, 0, stream>>>(w2_0, w2_1, w2_2, W2p);
    hipMemsetAsync(d_out, 0, (size_t)out_size * sizeof(float), stream);
    gemm1_k<<<dim3(8, 130), 256, 0, stream>>>(hs, W1p, b1_0, b1_1, b1_2, counts, idx, Hp);
    gemm2_k<<<dim3(25, 130), 256, 0, stream>>>(Hp, W2p, b2_0, b2_1, b2_2, counts, idx, Out);
}